// Round 4
// baseline (111.986 us; speedup 1.0000x reference)
//
#include <hip/hip_runtime.h>
#include <hip/hip_bf16.h>
#include <hip/hip_fp16.h>

#define K_DIM 4096
#define N_DIM 14336
#define B_M   32
#define KSPLIT 8
#define NSTEPS 128                    // K_DIM / 32
#define STEPS_PER (NSTEPS / KSPLIT)   // 16
#define NTILES (N_DIM / 16)           // 896
#define WPB 4                         // waves per block

typedef __attribute__((ext_vector_type(8))) short short8;
typedef __attribute__((ext_vector_type(4))) float f32x4;
typedef __attribute__((ext_vector_type(4))) int   i32x4;

static __device__ __forceinline__ short f2bf(float f) {
    union { float f; unsigned u; } v; v.f = f;
    unsigned r = v.u + 0x7FFFu + ((v.u >> 16) & 1u);   // RNE to bf16
    return (short)(r >> 16);
}

// Fused: dequant + GEMM + split-K via atomics. One wave owns one 16-col
// n-tile x 32 batch rows for one K-slice of 512 (16 MFMA steps).
__global__ __launch_bounds__(256) void fused_gemm_kernel(
        const int* __restrict__ qw, const float* __restrict__ x,
        const float* __restrict__ scales, const float* __restrict__ bias,
        float* __restrict__ out) {
    const int tid  = threadIdx.x;
    const int wave = tid >> 6;
    const int lane = tid & 63;
    const int g  = lane >> 4;                 // k-group 0..3
    const int nl = lane & 15;
    const int tile = blockIdx.x * WPB + wave;
    const int n = tile * 16 + nl;
    const int kslice = blockIdx.y;
    const int s0 = kslice * STEPS_PER;
    const int send = s0 + STEPS_PER;

    const int* qrow = qw + (size_t)n * K_DIM + 8 * g;
    const float* srow = scales + (size_t)n * (K_DIM / 64);  // f32 (harness upcasts fp16)
    const float* xr0 = x + (size_t)nl * K_DIM + 8 * g;      // batch rows nl and nl+16
    const float* xr1 = xr0 + (size_t)16 * K_DIM;

    f32x4 acc0 = {0.f, 0.f, 0.f, 0.f};
    f32x4 acc1 = {0.f, 0.f, 0.f, 0.f};

    // prefetch first K-step
    i32x4 qa = *(const i32x4*)(qrow + 32 * s0);
    i32x4 qb = *(const i32x4*)(qrow + 32 * s0 + 4);
    float sc = srow[s0 >> 1];

    #pragma unroll 4
    for (int s = s0; s < send; ++s) {
        int sn = s + 1; if (sn > NSTEPS - 1) sn = NSTEPS - 1;   // clamp: in-bounds
        i32x4 nqa = *(const i32x4*)(qrow + 32 * sn);
        i32x4 nqb = *(const i32x4*)(qrow + 32 * sn + 4);
        float nsc = srow[sn >> 1];

        // A fragments from x (f32 -> bf16), slot (g,j) <-> k = 32s + 8g + j
        f32x4 x00 = *(const f32x4*)(xr0 + 32 * s);
        f32x4 x01 = *(const f32x4*)(xr0 + 32 * s + 4);
        f32x4 x10 = *(const f32x4*)(xr1 + 32 * s);
        f32x4 x11 = *(const f32x4*)(xr1 + 32 * s + 4);
        short8 a0, a1;
        #pragma unroll
        for (int j = 0; j < 4; ++j) { a0[j] = f2bf(x00[j]); a0[j + 4] = f2bf(x01[j]); }
        #pragma unroll
        for (int j = 0; j < 4; ++j) { a1[j] = f2bf(x10[j]); a1[j + 4] = f2bf(x11[j]); }

        // dequant B fragment: w[n][32s + 8g + j] = q * scale (same slot->k map)
        short8 bw;
        bw[0] = f2bf((float)qa[0] * sc);
        bw[1] = f2bf((float)qa[1] * sc);
        bw[2] = f2bf((float)qa[2] * sc);
        bw[3] = f2bf((float)qa[3] * sc);
        bw[4] = f2bf((float)qb[0] * sc);
        bw[5] = f2bf((float)qb[1] * sc);
        bw[6] = f2bf((float)qb[2] * sc);
        bw[7] = f2bf((float)qb[3] * sc);

        acc0 = __builtin_amdgcn_mfma_f32_16x16x32_bf16(a0, bw, acc0, 0, 0, 0);
        acc1 = __builtin_amdgcn_mfma_f32_16x16x32_bf16(a1, bw, acc1, 0, 0, 0);

        qa = nqa; qb = nqb; sc = nsc;
    }

    // C/D layout (verified): col = lane&15 (n), row = 4*(lane>>4)+r (b)
    // Split-K reduction via device-scope f32 atomics; slice 0 carries bias.
    const float bv = (kslice == 0) ? bias[n] : 0.f;
    float* pp = out + n;
    #pragma unroll
    for (int r = 0; r < 4; ++r) {
        atomicAdd(&pp[(size_t)(4 * g + r) * N_DIM],      acc0[r] + bv);
        atomicAdd(&pp[(size_t)(16 + 4 * g + r) * N_DIM], acc1[r] + bv);
    }
}

extern "C" void kernel_launch(void* const* d_in, const int* in_sizes, int n_in,
                              void* d_out, int out_size, void* d_ws, size_t ws_size,
                              hipStream_t stream) {
    const float* x    = (const float*)d_in[0];
    const int*   qw   = (const int*)d_in[1];
    const float* sc   = (const float*)d_in[2];   // fp16 in reference, delivered as f32
    const float* bias = (const float*)d_in[3];
    float* out = (float*)d_out;

    hipMemsetAsync(out, 0, (size_t)out_size * sizeof(float), stream);
    fused_gemm_kernel<<<dim3(NTILES / WPB, KSPLIT), dim3(256), 0, stream>>>(
        qw, x, sc, bias, out);
}

// Round 5
// 52.494 us; speedup vs baseline: 2.1333x; 2.1333x over previous
//
#include <hip/hip_runtime.h>
#include <hip/hip_bf16.h>
#include <hip/hip_fp16.h>

#define K_DIM 4096
#define N_DIM 14336
#define B_M   32
#define KSPLIT 8
#define NSTEPS 128                    // K_DIM / 32 MFMA steps total
#define NTILES (N_DIM / 16)           // 896
#define BLK_TILES 4                   // n-tiles (=waves) per block
#define NBLOCKS (NTILES / BLK_TILES)  // 224
#define CHUNKS 8                      // chunks per K-slice
#define BK 64                         // k-ints per chunk (1 scale block)

typedef __attribute__((ext_vector_type(8))) short short8;
typedef __attribute__((ext_vector_type(4))) float f32x4;
typedef __attribute__((ext_vector_type(4))) int   i32x4;

static __device__ __forceinline__ short f2bf(float f) {
    union { float f; unsigned u; } v; v.f = f;
    unsigned r = v.u + 0x7FFFu + ((v.u >> 16) & 1u);   // RNE to bf16
    return (short)(r >> 16);
}

// Pre-swizzle x (32x4096 f32) into MFMA A-fragment order, bf16.
// xa[((s*2+f)*64 + lane)*8 + j] = bf16(x[16*f + (lane&15)][32*s + 8*(lane>>4) + j])
__global__ __launch_bounds__(256) void prep_xa_kernel(const float* __restrict__ x,
                                                      short* __restrict__ xa) {
    int t = blockIdx.x * 256 + threadIdx.x;   // 0 .. 131071
    int j = t & 7;
    int l = (t >> 3) & 63;
    int f = (t >> 9) & 1;
    int s = t >> 10;                          // 0 .. 127
    int m = 16 * f + (l & 15);
    int k = 32 * s + 8 * (l >> 4) + j;
    xa[t] = f2bf(x[(size_t)m * K_DIM + k]);
}

// LDS-staged dequant GEMM. Block = 4 waves; wave w owns n-tile (blockIdx.x*4+w)
// and LDS rows [w*16, w*16+16) — each wave reads only what it staged: no barriers.
// LDS layout per buffer: 64 rows x 16 units of 16B; linear unit p holds logical
// unit l = p ^ (row&7)  (XOR swizzle; applied on the GLOBAL source address at
// stage time since global_load_lds writes linearly, and re-applied on ds_read).
__global__ __launch_bounds__(256, 4) void gemm_lds_kernel(
        const int* __restrict__ qw, const short* __restrict__ xa,
        const float* __restrict__ scales, float* __restrict__ part) {
    __shared__ int ldsA[4096];   // 16 KB
    __shared__ int ldsB[4096];   // 16 KB

    const int tid  = threadIdx.x;
    const int w    = tid >> 6;
    const int lane = tid & 63;
    const int g    = lane >> 4;
    const int nl   = lane & 15;
    const int n0   = blockIdx.x * (BLK_TILES * 16);
    const int n    = n0 + w * 16 + nl;
    const int kslice = blockIdx.y;
    const int gc0  = kslice * CHUNKS;

    const float* srow = scales + (size_t)n * (K_DIM / 64);   // f32 (harness upcasts fp16)

    f32x4 acc0 = {0.f, 0.f, 0.f, 0.f};
    f32x4 acc1 = {0.f, 0.f, 0.f, 0.f};

    // ---- staging: 4 x global_load_lds(16B) per wave per chunk ----
    auto stage = [&](int* buf, int gc) {
        #pragma unroll
        for (int i = 0; i < 4; ++i) {
            int row = w * 16 + i * 4 + (lane >> 4);          // local row 0..63
            int l   = (lane & 15) ^ (row & 7);               // inverse swizzle on source
            const int* src = qw + (size_t)(n0 + row) * K_DIM + gc * BK + l * 4;
            __builtin_amdgcn_global_load_lds(
                (const __attribute__((address_space(1))) void*)src,
                (__attribute__((address_space(3))) void*)(buf + (w * 4 + i) * 256),
                16, 0, 0);
        }
    };

    // ---- compute one chunk (2 MFMA steps) from a staged buffer ----
    auto compute = [&](const int* buf, int gc) {
        float sc = srow[gc];                                  // one scale block per chunk
        const int base = (w * 16 + nl) * 64;                  // row base in ints
        #pragma unroll
        for (int sp = 0; sp < 2; ++sp) {
            int uA = 8 * sp + 2 * g;
            i32x4 qa = *(const i32x4*)(buf + base + ((uA    ) ^ (nl & 7)) * 4);
            i32x4 qb = *(const i32x4*)(buf + base + ((uA + 1) ^ (nl & 7)) * 4);

            int sg = gc * 2 + sp;                             // global MFMA step
            short8 a0 = *(const short8*)(xa + (size_t)sg * 1024 + lane * 8);
            short8 a1 = *(const short8*)(xa + (size_t)sg * 1024 + 512 + lane * 8);

            short8 bw;
            bw[0] = f2bf((float)qa[0] * sc);
            bw[1] = f2bf((float)qa[1] * sc);
            bw[2] = f2bf((float)qa[2] * sc);
            bw[3] = f2bf((float)qa[3] * sc);
            bw[4] = f2bf((float)qb[0] * sc);
            bw[5] = f2bf((float)qb[1] * sc);
            bw[6] = f2bf((float)qb[2] * sc);
            bw[7] = f2bf((float)qb[3] * sc);

            acc0 = __builtin_amdgcn_mfma_f32_16x16x32_bf16(a0, bw, acc0, 0, 0, 0);
            acc1 = __builtin_amdgcn_mfma_f32_16x16x32_bf16(a1, bw, acc1, 0, 0, 0);
        }
    };

    stage(ldsA, gc0);
    #pragma unroll
    for (int c = 0; c < CHUNKS; ++c) {
        int* cur = (c & 1) ? ldsB : ldsA;
        int* nxt = (c & 1) ? ldsA : ldsB;
        asm volatile("s_waitcnt vmcnt(0)" ::: "memory");      // chunk c's stage landed
        if (c + 1 < CHUNKS) stage(nxt, gc0 + c + 1);          // prefetch next chunk
        compute(cur, gc0 + c);
    }

    // C/D layout (verified): col = lane&15 (n), row = 4*(lane>>4)+r (b)
    float* pp = part + (size_t)kslice * B_M * N_DIM + n;
    #pragma unroll
    for (int r = 0; r < 4; ++r) {
        pp[(size_t)(4 * g + r) * N_DIM]      = acc0[r];
        pp[(size_t)(16 + 4 * g + r) * N_DIM] = acc1[r];
    }
}

__global__ __launch_bounds__(256) void reduce_kernel(const f32x4* __restrict__ part,
                                                     const f32x4* __restrict__ bias4,
                                                     f32x4* __restrict__ out4) {
    int i = blockIdx.x * 256 + threadIdx.x;   // 0 .. 114687 (32*14336/4)
    int b = i / (N_DIM / 4);
    int nq = i - b * (N_DIM / 4);
    f32x4 s = bias4[nq];
    #pragma unroll
    for (int ks = 0; ks < KSPLIT; ++ks)
        s += part[((size_t)(ks * B_M + b)) * (N_DIM / 4) + nq];
    out4[i] = s;
}

// Fallback (tiny ws): verified register-path kernel, full K per wave.
__global__ __launch_bounds__(64) void gemm_reg_kernel(
        const int* __restrict__ qw, const float* __restrict__ x,
        const float* __restrict__ scales, const float* __restrict__ bias,
        float* __restrict__ out) {
    const int lane = threadIdx.x;
    const int g = lane >> 4, nl = lane & 15;
    const int n = blockIdx.x * 16 + nl;
    const int* qrow = qw + (size_t)n * K_DIM + 8 * g;
    const float* srow = scales + (size_t)n * (K_DIM / 64);
    const float* xr0 = x + (size_t)nl * K_DIM + 8 * g;
    const float* xr1 = xr0 + (size_t)16 * K_DIM;
    f32x4 acc0 = {0.f,0.f,0.f,0.f}, acc1 = {0.f,0.f,0.f,0.f};
    for (int s = 0; s < NSTEPS; ++s) {
        i32x4 qa = *(const i32x4*)(qrow + 32 * s);
        i32x4 qb = *(const i32x4*)(qrow + 32 * s + 4);
        float sc = srow[s >> 1];
        f32x4 x00 = *(const f32x4*)(xr0 + 32 * s), x01 = *(const f32x4*)(xr0 + 32 * s + 4);
        f32x4 x10 = *(const f32x4*)(xr1 + 32 * s), x11 = *(const f32x4*)(xr1 + 32 * s + 4);
        short8 a0, a1, bw;
        #pragma unroll
        for (int j = 0; j < 4; ++j) { a0[j]=f2bf(x00[j]); a0[j+4]=f2bf(x01[j]);
                                      a1[j]=f2bf(x10[j]); a1[j+4]=f2bf(x11[j]);
                                      bw[j]=f2bf((float)qa[j]*sc); bw[j+4]=f2bf((float)qb[j]*sc); }
        acc0 = __builtin_amdgcn_mfma_f32_16x16x32_bf16(a0, bw, acc0, 0, 0, 0);
        acc1 = __builtin_amdgcn_mfma_f32_16x16x32_bf16(a1, bw, acc1, 0, 0, 0);
    }
    float bv = bias[n];
    float* pp = out + n;
    #pragma unroll
    for (int r = 0; r < 4; ++r) {
        pp[(size_t)(4 * g + r) * N_DIM]      = acc0[r] + bv;
        pp[(size_t)(16 + 4 * g + r) * N_DIM] = acc1[r] + bv;
    }
}

extern "C" void kernel_launch(void* const* d_in, const int* in_sizes, int n_in,
                              void* d_out, int out_size, void* d_ws, size_t ws_size,
                              hipStream_t stream) {
    const float* x    = (const float*)d_in[0];
    const int*   qw   = (const int*)d_in[1];
    const float* sc   = (const float*)d_in[2];   // fp16 in reference, delivered as f32
    const float* bias = (const float*)d_in[3];
    float* out = (float*)d_out;

    const size_t XA_BYTES   = (size_t)B_M * K_DIM * 2;            // 256 KB
    const size_t PART_BYTES = (size_t)KSPLIT * B_M * N_DIM * 4;   // 14.7 MB

    if (ws_size >= XA_BYTES + PART_BYTES) {
        short* xa   = (short*)d_ws;
        float* part = (float*)((char*)d_ws + XA_BYTES);
        prep_xa_kernel<<<dim3(512), dim3(256), 0, stream>>>(x, xa);
        gemm_lds_kernel<<<dim3(NBLOCKS, KSPLIT), dim3(256), 0, stream>>>(qw, xa, sc, part);
        reduce_kernel<<<dim3((B_M * N_DIM / 4) / 256), dim3(256), 0, stream>>>(
            (const f32x4*)part, (const f32x4*)bias, (f32x4*)out);
    } else {
        gemm_reg_kernel<<<dim3(NTILES), dim3(64), 0, stream>>>(qw, x, sc, bias, out);
    }
}

// Round 6
// 48.061 us; speedup vs baseline: 2.3301x; 1.0922x over previous
//
#include <hip/hip_runtime.h>
#include <hip/hip_bf16.h>
#include <hip/hip_fp16.h>

#define K_DIM 4096
#define N_DIM 14336
#define B_M   32
#define NSTEPS 128                    // K_DIM / 32 MFMA steps total
#define NTILES (N_DIM / 16)           // 896 blocks, one n-tile each
#define WAVES 4                       // waves per block, one K-slice each
#define WCHUNKS 16                    // 64-int chunks per wave (K-slice = 1024 ints)

typedef __attribute__((ext_vector_type(8))) short short8;
typedef __attribute__((ext_vector_type(4))) float f32x4;
typedef __attribute__((ext_vector_type(4))) int   i32x4;

static __device__ __forceinline__ short f2bf(float f) {
    union { float f; unsigned u; } v; v.f = f;
    unsigned r = v.u + 0x7FFFu + ((v.u >> 16) & 1u);   // RNE to bf16
    return (short)(r >> 16);
}

// Pre-swizzle x (32x4096 f32) into MFMA A-fragment order, bf16.
// xa[((s*2+f)*64 + lane)*8 + j] = bf16(x[16*f + (lane&15)][32*s + 8*(lane>>4) + j])
__global__ __launch_bounds__(256) void prep_xa_kernel(const float* __restrict__ x,
                                                      short* __restrict__ xa) {
    int t = blockIdx.x * 256 + threadIdx.x;   // 0 .. 131071
    int j = t & 7;
    int l = (t >> 3) & 63;
    int f = (t >> 9) & 1;
    int s = t >> 10;                          // 0 .. 127
    int m = 16 * f + (l & 15);
    int k = 32 * s + 8 * (l >> 4) + j;
    xa[t] = f2bf(x[(size_t)m * K_DIM + k]);
}

// One block = one 16-col n-tile. Wave w handles K-slice [w*1024, w*1024+1024)
// (16 chunks of 64 ints), staging its own 16-row x 256B chunks through its own
// LDS region (no barriers in the loop), then a single cross-wave LDS reduce.
// LDS chunk layout per wave: 16 rows x 16 units(16B); linear unit p at row r
// holds logical unit p ^ (r&7) (inverse swizzle applied on global source).
__global__ __launch_bounds__(256, 4) void gemm_lds_kernel(
        const int* __restrict__ qw, const short* __restrict__ xa,
        const float* __restrict__ scales, const float* __restrict__ bias,
        float* __restrict__ out) {
    __shared__ int ldsA[4096];   // 4 waves x 1024 ints (4 KB each)
    __shared__ int ldsB[4096];

    const int tid  = threadIdx.x;
    const int w    = tid >> 6;
    const int lane = tid & 63;
    const int g    = lane >> 4;
    const int nl   = lane & 15;
    const int n0   = blockIdx.x * 16;
    const int n    = n0 + nl;
    const int gc0  = w * WCHUNKS;             // this wave's first chunk index

    const float* srow = scales + (size_t)n * (K_DIM / 64);  // f32 (harness upcasts fp16)

    f32x4 acc0 = {0.f, 0.f, 0.f, 0.f};
    f32x4 acc1 = {0.f, 0.f, 0.f, 0.f};

    // ---- staging: 4 x global_load_lds(16B) per chunk (instr i -> rows 4i..4i+3) ----
    auto stage = [&](int* wbuf, int gc) {
        #pragma unroll
        for (int i = 0; i < 4; ++i) {
            int row = i * 4 + (lane >> 4);            // tile-local row 0..15
            int l   = (lane & 15) ^ (row & 7);        // inverse swizzle on source
            const int* src = qw + (size_t)(n0 + row) * K_DIM + gc * 64 + l * 4;
            __builtin_amdgcn_global_load_lds(
                (const __attribute__((address_space(1))) void*)src,
                (__attribute__((address_space(3))) void*)(wbuf + i * 256),
                16, 0, 0);
        }
    };

    // ---- compute one chunk (2 MFMA steps) ----
    auto compute = [&](const int* wbuf, int gc) {
        float sc = srow[gc];                          // one scale block per chunk
        const int base = nl * 64;                     // this lane's row
        #pragma unroll
        for (int sp = 0; sp < 2; ++sp) {
            int uA = 8 * sp + 2 * g;
            i32x4 qa = *(const i32x4*)(wbuf + base + ((uA    ) ^ (nl & 7)) * 4);
            i32x4 qb = *(const i32x4*)(wbuf + base + ((uA + 1) ^ (nl & 7)) * 4);

            int sg = gc * 2 + sp;                     // global MFMA step 0..127
            short8 a0 = *(const short8*)(xa + (size_t)sg * 1024 + lane * 8);
            short8 a1 = *(const short8*)(xa + (size_t)sg * 1024 + 512 + lane * 8);

            short8 bw;
            bw[0] = f2bf((float)qa[0] * sc);
            bw[1] = f2bf((float)qa[1] * sc);
            bw[2] = f2bf((float)qa[2] * sc);
            bw[3] = f2bf((float)qa[3] * sc);
            bw[4] = f2bf((float)qb[0] * sc);
            bw[5] = f2bf((float)qb[1] * sc);
            bw[6] = f2bf((float)qb[2] * sc);
            bw[7] = f2bf((float)qb[3] * sc);

            acc0 = __builtin_amdgcn_mfma_f32_16x16x32_bf16(a0, bw, acc0, 0, 0, 0);
            acc1 = __builtin_amdgcn_mfma_f32_16x16x32_bf16(a1, bw, acc1, 0, 0, 0);
        }
    };

    int* bufA = ldsA + w * 1024;
    int* bufB = ldsB + w * 1024;

    stage(bufA, gc0);
    #pragma unroll
    for (int c = 0; c < WCHUNKS; ++c) {
        int* cur = (c & 1) ? bufB : bufA;
        int* nxt = (c & 1) ? bufA : bufB;
        asm volatile("s_waitcnt vmcnt(0)" ::: "memory");   // chunk c staged
        if (c + 1 < WCHUNKS) stage(nxt, gc0 + c + 1);      // prefetch next
        compute(cur, gc0 + c);
    }

    // ---- cross-wave reduce: acc -> own LDS region, barrier, tree-sum ----
    float* fb = (float*)(ldsA + w * 1024);
    #pragma unroll
    for (int r = 0; r < 4; ++r) { fb[lane * 8 + r] = acc0[r]; fb[lane * 8 + 4 + r] = acc1[r]; }
    __syncthreads();

    // 256 threads x 2 components: thread handles (lane2, rr) and (lane2, rr+4)
    const int lane2 = tid & 63;
    const int rr    = tid >> 6;           // 0..3
    const int g2    = lane2 >> 4;
    const int n2    = n0 + (lane2 & 15);
    float s1 = 0.f, s2 = 0.f;
    #pragma unroll
    for (int ww = 0; ww < WAVES; ++ww) {
        const float* fw = (const float*)(ldsA + ww * 1024);
        s1 += fw[lane2 * 8 + rr];
        s2 += fw[lane2 * 8 + 4 + rr];
    }
    const float bv = bias[n2];
    out[(size_t)(4 * g2 + rr) * N_DIM + n2]      = s1 + bv;   // C/D row = 4*(lane>>4)+r
    out[(size_t)(16 + 4 * g2 + rr) * N_DIM + n2] = s2 + bv;
}

// Fallback (tiny ws): verified register-path kernel, full K per wave.
__global__ __launch_bounds__(64) void gemm_reg_kernel(
        const int* __restrict__ qw, const float* __restrict__ x,
        const float* __restrict__ scales, const float* __restrict__ bias,
        float* __restrict__ out) {
    const int lane = threadIdx.x;
    const int g = lane >> 4, nl = lane & 15;
    const int n = blockIdx.x * 16 + nl;
    const int* qrow = qw + (size_t)n * K_DIM + 8 * g;
    const float* srow = scales + (size_t)n * (K_DIM / 64);
    const float* xr0 = x + (size_t)nl * K_DIM + 8 * g;
    const float* xr1 = xr0 + (size_t)16 * K_DIM;
    f32x4 acc0 = {0.f,0.f,0.f,0.f}, acc1 = {0.f,0.f,0.f,0.f};
    for (int s = 0; s < NSTEPS; ++s) {
        i32x4 qa = *(const i32x4*)(qrow + 32 * s);
        i32x4 qb = *(const i32x4*)(qrow + 32 * s + 4);
        float sc = srow[s >> 1];
        f32x4 x00 = *(const f32x4*)(xr0 + 32 * s), x01 = *(const f32x4*)(xr0 + 32 * s + 4);
        f32x4 x10 = *(const f32x4*)(xr1 + 32 * s), x11 = *(const f32x4*)(xr1 + 32 * s + 4);
        short8 a0, a1, bw;
        #pragma unroll
        for (int j = 0; j < 4; ++j) { a0[j]=f2bf(x00[j]); a0[j+4]=f2bf(x01[j]);
                                      a1[j]=f2bf(x10[j]); a1[j+4]=f2bf(x11[j]);
                                      bw[j]=f2bf((float)qa[j]*sc); bw[j+4]=f2bf((float)qb[j]*sc); }
        acc0 = __builtin_amdgcn_mfma_f32_16x16x32_bf16(a0, bw, acc0, 0, 0, 0);
        acc1 = __builtin_amdgcn_mfma_f32_16x16x32_bf16(a1, bw, acc1, 0, 0, 0);
    }
    float bv = bias[n];
    float* pp = out + n;
    #pragma unroll
    for (int r = 0; r < 4; ++r) {
        pp[(size_t)(4 * g + r) * N_DIM]      = acc0[r] + bv;
        pp[(size_t)(16 + 4 * g + r) * N_DIM] = acc1[r] + bv;
    }
}

extern "C" void kernel_launch(void* const* d_in, const int* in_sizes, int n_in,
                              void* d_out, int out_size, void* d_ws, size_t ws_size,
                              hipStream_t stream) {
    const float* x    = (const float*)d_in[0];
    const int*   qw   = (const int*)d_in[1];
    const float* sc   = (const float*)d_in[2];   // fp16 in reference, delivered as f32
    const float* bias = (const float*)d_in[3];
    float* out = (float*)d_out;

    const size_t XA_BYTES = (size_t)B_M * K_DIM * 2;   // 256 KB

    if (ws_size >= XA_BYTES) {
        short* xa = (short*)d_ws;
        prep_xa_kernel<<<dim3(512), dim3(256), 0, stream>>>(x, xa);
        gemm_lds_kernel<<<dim3(NTILES), dim3(256), 0, stream>>>(qw, xa, sc, bias, out);
    } else {
        gemm_reg_kernel<<<dim3(NTILES), dim3(64), 0, stream>>>(qw, x, sc, bias, out);
    }
}